// Round 11
// baseline (966.135 us; speedup 1.0000x reference)
//
#include <hip/hip_runtime.h>

#define EMBED 128
#define OUT_EMBED 256
#define NUM_RBF 6
#define N_EDGES_C 640000
#define N_PARTICLES_C 20000

typedef __attribute__((ext_vector_type(8))) short short8;
typedef __attribute__((ext_vector_type(4))) float f32x4;
typedef unsigned int u32;
typedef unsigned short u16;

__device__ __forceinline__ u16 f32_to_bf16(float f) {
    u32 u = __float_as_uint(f);
    u = u + 0x7fff + ((u >> 16) & 1);   // RNE
    return (u16)(u >> 16);
}
__device__ __forceinline__ float bf16_to_f32(u16 h) {
    return __uint_as_float(((u32)h) << 16);
}
__device__ __forceinline__ u32 pack_hilo(float f) {
    u16 hi = f32_to_bf16(f);
    float rem = f - bf16_to_f32(hi);
    u16 lo = f32_to_bf16(rem);
    return ((u32)hi << 16) | lo;
}
__device__ __forceinline__ float unpack_f32(u32 v) {
    return __uint_as_float(v & 0xffff0000u) + __uint_as_float(v << 16);
}

// ---------------------------------------------------------------------------
// Edge phase: counting-sort CSR + gather (atomic-free accumulation).
// ---------------------------------------------------------------------------
__global__ __launch_bounds__(256) void hist_kernel(
    const int* __restrict__ idx_i, int* __restrict__ counts)
{
    const int e = blockIdx.x * 256 + threadIdx.x;
    if (e < N_EDGES_C) atomicAdd(&counts[idx_i[e]], 1);
}

// shfl-based exclusive scan of counts[20000] -> offsets[20001], cursor.
__global__ __launch_bounds__(1024) void scan_kernel(
    const int* __restrict__ counts, int* __restrict__ offsets,
    int* __restrict__ cursor)
{
    __shared__ int wsum[16];
    __shared__ int wpre[17];
    __shared__ int carry;
    const int tid  = threadIdx.x;
    const int lane = tid & 63;
    const int wid  = tid >> 6;
    if (tid == 0) carry = 0;
    __syncthreads();
    for (int base = 0; base < N_PARTICLES_C; base += 1024) {
        const int idx = base + tid;
        int v = (idx < N_PARTICLES_C) ? counts[idx] : 0;
        int x = v;
        #pragma unroll
        for (int off = 1; off < 64; off <<= 1) {
            int t = __shfl_up(x, off);
            if (lane >= off) x += t;
        }
        if (lane == 63) wsum[wid] = x;
        __syncthreads();
        if (tid == 0) {
            int run = 0;
            #pragma unroll
            for (int i = 0; i < 16; ++i) { wpre[i] = run; run += wsum[i]; }
            wpre[16] = run;
        }
        __syncthreads();
        const int excl = carry + wpre[wid] + x - v;
        if (idx < N_PARTICLES_C) { offsets[idx] = excl; cursor[idx] = excl; }
        __syncthreads();
        if (tid == 0) carry += wpre[16];
        __syncthreads();
    }
    if (threadIdx.x == 0) offsets[N_PARTICLES_C] = carry;
}

__global__ __launch_bounds__(256) void scatter_kernel(
    const int* __restrict__ idx_i, int* __restrict__ cursor,
    int* __restrict__ sorted_eid)
{
    const int e = blockIdx.x * 256 + threadIdx.x;
    if (e < N_EDGES_C) {
        const int p = idx_i[e];
        const int pos = atomicAdd(&cursor[p], 1);
        sorted_eid[pos] = e;
    }
}

// One wave per particle; 2-edge unroll for memory-level parallelism.
__global__ __launch_bounds__(256) void gather_kernel(
    const float* __restrict__ messages,
    const float* __restrict__ rbf,
    const float* __restrict__ W_rbf,
    const int*   __restrict__ offsets,
    const int*   __restrict__ sorted_eid,
    u32* __restrict__ summed_hilo)
{
    const int wid  = threadIdx.x >> 6;
    const int lane = threadIdx.x & 63;
    const int p    = blockIdx.x * 4 + wid;
    const int c2   = lane * 2;

    float w0[NUM_RBF], w1[NUM_RBF];
    #pragma unroll
    for (int k = 0; k < NUM_RBF; ++k) {
        w0[k] = W_rbf[k * EMBED + c2];
        w1[k] = W_rbf[k * EMBED + c2 + 1];
    }

    const int jb = offsets[p];
    const int je = offsets[p + 1];
    float a0 = 0.f, a1 = 0.f;
    int j = jb;
    for (; j + 2 <= je; j += 2) {
        const int e0 = sorted_eid[j];
        const int e1 = sorted_eid[j + 1];
        const float2 m0v = *(const float2*)&messages[(size_t)e0 * EMBED + c2];
        const float2 m1v = *(const float2*)&messages[(size_t)e1 * EMBED + c2];
        float r0[NUM_RBF], r1[NUM_RBF];
        #pragma unroll
        for (int k = 0; k < NUM_RBF; ++k) {
            r0[k] = rbf[e0 * NUM_RBF + k];
            r1[k] = rbf[e1 * NUM_RBF + k];
        }
        float g00 = 0.f, g01 = 0.f, g10 = 0.f, g11 = 0.f;
        #pragma unroll
        for (int k = 0; k < NUM_RBF; ++k) {
            g00 = fmaf(r0[k], w0[k], g00);
            g01 = fmaf(r0[k], w1[k], g01);
            g10 = fmaf(r1[k], w0[k], g10);
            g11 = fmaf(r1[k], w1[k], g11);
        }
        a0 = fmaf(m0v.x, g00, a0);
        a1 = fmaf(m0v.y, g01, a1);
        a0 = fmaf(m1v.x, g10, a0);
        a1 = fmaf(m1v.y, g11, a1);
    }
    if (j < je) {
        const int e = sorted_eid[j];
        const float2 m = *(const float2*)&messages[(size_t)e * EMBED + c2];
        float r[NUM_RBF];
        #pragma unroll
        for (int k = 0; k < NUM_RBF; ++k) r[k] = rbf[e * NUM_RBF + k];
        float g0 = 0.f, g1 = 0.f;
        #pragma unroll
        for (int k = 0; k < NUM_RBF; ++k) {
            g0 = fmaf(r[k], w0[k], g0);
            g1 = fmaf(r[k], w1[k], g1);
        }
        a0 = fmaf(m.x, g0, a0);
        a1 = fmaf(m.y, g1, a1);
    }
    uint2 outv;
    outv.x = pack_hilo(a0);
    outv.y = pack_hilo(a1);
    *(uint2*)&summed_hilo[(size_t)p * EMBED + c2] = outv;
}

// ---------------------------------------------------------------------------
// Weight conversion: f32 [K][N] -> fragment-linear bf16 hi/lo planes.
// frag element e = ((kt*16 + nt)*64 + lane)*8 + j  maps to
//   W[kt*32 + (lane>>4)*8 + j][nt*16 + (lane&15)]
// ---------------------------------------------------------------------------
__global__ __launch_bounds__(256) void convert_weights_kernel(
    const float* __restrict__ W_up,      // 128x256
    const float* __restrict__ W_dense,   // 3x256x256
    u16* __restrict__ w1hi, u16* __restrict__ w1lo,
    u16* __restrict__ wdhi, u16* __restrict__ wdlo)
{
    const int gid = blockIdx.x * 256 + threadIdx.x;   // 0 .. 229375
    if (gid < 32768) {
        const int e = gid;
        const int j = e & 7, lane = (e >> 3) & 63, nt = (e >> 9) & 15, kt = e >> 13;
        const int k = kt * 32 + (lane >> 4) * 8 + j;
        const int n = nt * 16 + (lane & 15);
        const float w = W_up[k * 256 + n];
        const u16 hi = f32_to_bf16(w);
        w1hi[e] = hi;
        w1lo[e] = f32_to_bf16(w - bf16_to_f32(hi));
    } else {
        const int t = gid - 32768;                    // 0 .. 196607
        const int layer = t >> 16;                    // 65536 per layer
        const int e = t & 65535;
        const int j = e & 7, lane = (e >> 3) & 63, nt = (e >> 9) & 15, kt = e >> 13;
        const int k = kt * 32 + (lane >> 4) * 8 + j;
        const int n = nt * 16 + (lane & 15);
        const float w = W_dense[layer * 65536 + k * 256 + n];
        const u16 hi = f32_to_bf16(w);
        wdhi[t] = hi;
        wdlo[t] = f32_to_bf16(w - bf16_to_f32(hi));
    }
}

// ---------------------------------------------------------------------------
// Split-bf16 MFMA dense layer, B-frags straight from global (L2-resident):
// no k-loop barriers, no LDS bank conflicts. LDS only for C-tile epilogue.
// FINAL: fuse out = h @ W_final, skip C store.
// ---------------------------------------------------------------------------
template<int K, bool BIAS, bool SWISH, bool FINAL>
__global__ __launch_bounds__(256) void mfma_dense_kernel(
    const u32* __restrict__ A,
    const u16* __restrict__ Whi,
    const u16* __restrict__ Wlo,
    const float* __restrict__ bias,
    u32* __restrict__ C,
    const float* __restrict__ Wf,
    float* __restrict__ out,
    int M)
{
    static_assert(K % 32 == 0, "K must be multiple of 32");
    constexpr int NKT = K / 32;
    __shared__ u32 smem[16384];            // 64 KB C-tile (epilogue only)

    const int tid  = threadIdx.x;
    const int wave = tid >> 6;
    const int lane = tid & 63;
    const int m0b  = blockIdx.x * 64;
    const int m0   = m0b + wave * 16;

    int rA = m0 + (lane & 15);
    if (rA > M - 1) rA = M - 1;
    const u32* arow = A + (size_t)rA * K;

    f32x4 acc[16];
    #pragma unroll
    for (int nt = 0; nt < 16; ++nt) acc[nt] = (f32x4){0.f, 0.f, 0.f, 0.f};

    const short8* bhiG = (const short8*)Whi;
    const short8* bloG = (const short8*)Wlo;

    for (int kt = 0; kt < NKT; ++kt) {
        // A fragment: 8 packed u32 -> hi/lo short8
        const u32* ap = arow + kt * 32 + (lane >> 4) * 8;
        uint4 a01 = *(const uint4*)ap;
        uint4 a23 = *(const uint4*)(ap + 4);
        short8 ahi, alo;
        u32 av[8] = {a01.x, a01.y, a01.z, a01.w, a23.x, a23.y, a23.z, a23.w};
        #pragma unroll
        for (int j = 0; j < 8; ++j) {
            ahi[j] = (short)(av[j] >> 16);
            alo[j] = (short)(av[j] & 0xffff);
        }

        const int bbase = kt * 16 * 64 + lane;
        #pragma unroll 4
        for (int nt = 0; nt < 16; ++nt) {
            const short8 bhi = bhiG[bbase + nt * 64];
            const short8 blo = bloG[bbase + nt * 64];
            acc[nt] = __builtin_amdgcn_mfma_f32_16x16x32_bf16(ahi, bhi, acc[nt], 0, 0, 0);
            acc[nt] = __builtin_amdgcn_mfma_f32_16x16x32_bf16(alo, bhi, acc[nt], 0, 0, 0);
            acc[nt] = __builtin_amdgcn_mfma_f32_16x16x32_bf16(ahi, blo, acc[nt], 0, 0, 0);
        }
    }

    // epilogue: bias + swish into LDS C-tile
    #pragma unroll
    for (int nt = 0; nt < 16; ++nt) {
        const int col = nt * 16 + (lane & 15);
        float b = 0.f;
        if (BIAS) b = bias[col];
        #pragma unroll
        for (int r = 0; r < 4; ++r) {
            const int row_l = wave * 16 + (lane >> 4) * 4 + r;
            float v = acc[nt][r];
            if (BIAS)  v += b;
            if (SWISH) v = v / (1.f + __expf(-v));
            smem[row_l * 256 + col] = FINAL ? __float_as_uint(v) : pack_hilo(v);
        }
    }
    __syncthreads();

    if (FINAL) {
        // out[row] = h[row] . Wf ; C-tile holds f32 h
        const int row = tid >> 2;          // 0..63
        const int q   = tid & 3;           // quarter of the 256 cols
        float s = 0.f;
        const float4* wf4 = (const float4*)(Wf + q * 64);
        const u32* hrow = smem + row * 256 + q * 64;
        #pragma unroll
        for (int i = 0; i < 16; ++i) {
            const float4 w = wf4[i];
            s += __uint_as_float(hrow[i * 4 + 0]) * w.x
               + __uint_as_float(hrow[i * 4 + 1]) * w.y
               + __uint_as_float(hrow[i * 4 + 2]) * w.z
               + __uint_as_float(hrow[i * 4 + 3]) * w.w;
        }
        s += __shfl_xor(s, 1);
        s += __shfl_xor(s, 2);
        if (q == 0 && m0b + row < M) out[m0b + row] = s;
    } else {
        const uint4* csrc = (const uint4*)smem;     // 4096 uint4, 64 per row
        #pragma unroll
        for (int i = 0; i < 16; ++i) {
            const int idx = tid + i * 256;
            const int row = m0b + (idx >> 6);
            if (row < M)
                ((uint4*)(C + (size_t)row * 256))[idx & 63] = csrc[idx];
        }
    }
}

extern "C" void kernel_launch(void* const* d_in, const int* in_sizes, int n_in,
                              void* d_out, int out_size, void* d_ws, size_t ws_size,
                              hipStream_t stream) {
    const float* messages = (const float*)d_in[0];
    const float* rbf      = (const float*)d_in[1];
    const int*   idx_i    = (const int*)d_in[2];
    const float* W_rbf    = (const float*)d_in[4];
    const float* W_up     = (const float*)d_in[5];
    const float* W_dense  = (const float*)d_in[6];
    const float* b_dense  = (const float*)d_in[7];
    const float* W_final  = (const float*)d_in[8];
    float* out = (float*)d_out;

    // workspace layout (u32 units)
    u32* ws          = (u32*)d_ws;
    u32* summed_hilo = ws;                                    // 20000*128
    u32* hA          = summed_hilo + (size_t)N_PARTICLES_C * EMBED;   // 20000*256
    u32* hB          = hA + (size_t)N_PARTICLES_C * OUT_EMBED;        // 20000*256
    u16* w1hi        = (u16*)(hB + (size_t)N_PARTICLES_C * OUT_EMBED);
    u16* w1lo        = w1hi + 32768;
    u16* wdhi        = w1lo + 32768;
    u16* wdlo        = wdhi + 3 * 65536;
    // int scratch aliased into hA region (dead before dense1 writes hA)
    int* counts      = (int*)hA;
    int* offsets     = counts + N_PARTICLES_C;
    int* cursor      = offsets + N_PARTICLES_C + 1;
    int* sorted_eid  = cursor + N_PARTICLES_C;

    convert_weights_kernel<<<896, 256, 0, stream>>>(W_up, W_dense, w1hi, w1lo, wdhi, wdlo);

    hipMemsetAsync(counts, 0, N_PARTICLES_C * sizeof(int), stream);
    hist_kernel<<<N_EDGES_C / 256, 256, 0, stream>>>(idx_i, counts);
    scan_kernel<<<1, 1024, 0, stream>>>(counts, offsets, cursor);
    scatter_kernel<<<N_EDGES_C / 256, 256, 0, stream>>>(idx_i, cursor, sorted_eid);
    gather_kernel<<<N_PARTICLES_C / 4, 256, 0, stream>>>(
        messages, rbf, W_rbf, offsets, sorted_eid, summed_hilo);

    const int gdense = (N_PARTICLES_C + 63) / 64;
    mfma_dense_kernel<EMBED, false, false, false><<<gdense, 256, 0, stream>>>(
        summed_hilo, w1hi, w1lo, nullptr, hA, nullptr, nullptr, N_PARTICLES_C);
    mfma_dense_kernel<OUT_EMBED, true, true, false><<<gdense, 256, 0, stream>>>(
        hA, wdhi + 0 * 65536, wdlo + 0 * 65536, b_dense + 0 * OUT_EMBED, hB, nullptr, nullptr, N_PARTICLES_C);
    mfma_dense_kernel<OUT_EMBED, true, true, false><<<gdense, 256, 0, stream>>>(
        hB, wdhi + 1 * 65536, wdlo + 1 * 65536, b_dense + 1 * OUT_EMBED, hA, nullptr, nullptr, N_PARTICLES_C);
    mfma_dense_kernel<OUT_EMBED, true, true, true><<<gdense, 256, 0, stream>>>(
        hA, wdhi + 2 * 65536, wdlo + 2 * 65536, b_dense + 2 * OUT_EMBED, hB, W_final, out, N_PARTICLES_C);
}